// Round 24
// baseline (583.113 us; speedup 1.0000x reference)
//
#include <hip/hip_runtime.h>
#include <math.h>

#define NB 8
#define NC 32
#define NF 40
#define NT 2000
#define KW 637
#define PADW 318
#define TPB 256
#define HALFT 1000
#define XLN  (NT + 2 * PADW)   // 2636 real entries
#define XLNP 2656              // zero-padded (max window over-read 2647)
#define WMAX 5120              // floats; worst group needs 2*2484 = 4968
#define FG 4                   // freq groups: fi = g + FG*j (balanced taps)
#define NFG (NF / FG)

#define XSIZE (NB * NC * NT)   // 512000 (fp32)
#define KC 320                 // Eigen gebp kc (proven R21)

#define DET  3e-4f   // |im| margin: fast-path noise ~3e-6 -> 100x headroom
#define DET2 1e-7f   // |z|^2 near-origin margin

// canvas position (row*5+col) for each of the 32 channels; holes at 0,2,4
__device__ __constant__ int POS[32] = {
  1,3,5,6,7,8,9,10,11,13,14,15,16,12,18,19,20,21,17,22,23,24,25,26,
  27,28,29,30,31,32,33,34
};

__global__ __launch_bounds__(TPB)
void cwt_zero_holes(float* __restrict__ out) {
  int row = blockIdx.x;
  int p = (row % 3) * 2;          // hole canvas positions 0,2,4
  int rest = row / 3;
  size_t base = ((size_t)rest * 35 + p) * NT;
  float4 z = make_float4(0.f, 0.f, 0.f, 0.f);
  for (int t = threadIdx.x * 4; t < NT; t += TPB * 4)
    *(float4*)&out[base + t] = z;
}

// Exact Eigen-order recompute (kc=320, seq k-asc mul-then-add); x from LDS
// full row (window of output t starts at xp[t]), weights from global.
__device__ __noinline__ float2 fixup_point(const float* __restrict__ xv,
                                           const float* __restrict__ wr,
                                           const float* __restrict__ wi) {
  float b0r = 0.f, b0i = 0.f;
  #pragma unroll 4
  for (int k = 0; k < KC; ++k) {
    const float v = xv[k];
    b0r = __fadd_rn(b0r, __fmul_rn(wr[k], v));
    b0i = __fadd_rn(b0i, __fmul_rn(wi[k], v));
  }
  float b1r = 0.f, b1i = 0.f;
  #pragma unroll 4
  for (int k = KC; k < KW; ++k) {
    const float v = xv[k];
    b1r = __fadd_rn(b1r, __fmul_rn(wr[k], v));
    b1i = __fadd_rn(b1i, __fmul_rn(wi[k], v));
  }
  const float re = __fadd_rn(b0r, b1r);
  const float im = __fadd_rn(b0i, b1i);
  return make_float2(sqrtf(__fadd_rn(__fmul_rn(re, re), __fmul_rn(im, im))),
                     atan2f(im, re));
}

__device__ __forceinline__ void support_window(int fi, int& klo, int& kend,
                                               int& Lp) {
  const float cyc = (fi == 0) ? 4.0f
                  : (fi == 1) ? (4.0f + 2.0f / 3.0f)
                  : (fi == 2) ? (4.0f + 4.0f / 3.0f) : 6.0f;
  const float sigma = cyc / (6.283185307179586f * (float)(fi + 1));
  int h = (int)ceilf(6.0f * sigma * 250.0f);
  if (h > PADW) h = PADW;
  klo  = (PADW - h) & ~3;
  kend = PADW + h + 1;
  Lp   = (kend - klo + 3) & ~3;   // zero-padded length (multiple of 4)
}

__global__ __launch_bounds__(TPB)
void cwt_fast(const float* __restrict__ x,
              const float* __restrict__ W,
              float* __restrict__ out) {
  __shared__ __align__(16) float xp[XLNP];
  __shared__ __align__(16) float wlds[WMAX];

  const int bid = blockIdx.x;           // (b*32+c)*FG + g
  const int g   = bid & (FG - 1);
  const int bc  = bid >> 2;
  const int b   = bc >> 5;
  const int c   = bc & 31;
  const int tid = threadIdx.x;

  const float* __restrict__ xrow = x + (size_t)(b * NC + c) * NT;

  // stage FULL reflect-padded row (+ zero tail for window over-read)
  for (int i = tid; i < XLNP; i += TPB) {
    float v = 0.f;
    if (i < XLN) {
      int s = i - PADW;
      int m = (s < 0) ? -s : ((s >= NT) ? (2 * NT - 2 - s) : s);
      v = xrow[m];
    }
    xp[i] = v;
  }

  // stage all 10 truncated weight windows (zero-padded to 4-wide)
  {
    int woff = 0;
    for (int j = 0; j < NFG; ++j) {
      const int fi = g + FG * j;
      int klo, kend, Lp;
      support_window(fi, klo, kend, Lp);
      const float* __restrict__ wr_g = W + (size_t)(2 * fi) * KW;
      const float* __restrict__ wi_g = wr_g + KW;
      for (int i = tid; i < Lp; i += TPB) {
        const int k = klo + i;
        const bool in = k < kend;
        wlds[woff + i]      = in ? wr_g[k] : 0.f;
        wlds[woff + Lp + i] = in ? wi_g[k] : 0.f;
      }
      woff += 2 * Lp;
    }
  }
  __syncthreads();                      // the ONLY barrier

  const bool active = (tid < HALFT / 4);            // 250 threads
  const int ta = tid * 4;                            // half-0 outputs
  const int tb = tid * 4 + HALFT;                    // half-1 outputs
  const int pos = POS[c];
  const float4* __restrict__ xp4 = (const float4*)xp;

  int woff = 0;
  for (int j = 0; j < NFG; ++j) {
    const int fi = g + FG * j;
    int klo, kend, Lp;
    support_window(fi, klo, kend, Lp);
    const float* __restrict__ wr = wlds + woff;
    const float* __restrict__ wi = wr + Lp;
    woff += 2 * Lp;
    if (!active) continue;

    const int nst = Lp >> 2;
    const int ia0 = (ta + klo) >> 2;
    const int ib0 = (tb + klo) >> 2;
    float4 a0 = xp4[ia0], a1 = xp4[ia0 + 1];
    float4 b0 = xp4[ib0], b1 = xp4[ib0 + 1];

    float rea[4] = {0.f,0.f,0.f,0.f}, ima[4] = {0.f,0.f,0.f,0.f};
    float reb[4] = {0.f,0.f,0.f,0.f}, imb[4] = {0.f,0.f,0.f,0.f};

    for (int s = 0; s < nst; ++s) {
      const float4 wr4 = ((const float4*)wr)[s];   // broadcast, conflict-free
      const float4 wi4 = ((const float4*)wi)[s];
      const float4 a2 = xp4[ia0 + s + 2];          // slide prefetch
      const float4 b2 = xp4[ib0 + s + 2];
      const float va[8] = {a0.x,a0.y,a0.z,a0.w, a1.x,a1.y,a1.z,a1.w};
      const float vb[8] = {b0.x,b0.y,b0.z,b0.w, b1.x,b1.y,b1.z,b1.w};
      const float wrA[4] = {wr4.x, wr4.y, wr4.z, wr4.w};
      const float wiA[4] = {wi4.x, wi4.y, wi4.z, wi4.w};
      #pragma unroll
      for (int u = 0; u < 4; ++u) {
        #pragma unroll
        for (int q = 0; q < 4; ++q) {
          rea[q] = __fmaf_rn(va[u + q], wrA[u], rea[q]);
          ima[q] = __fmaf_rn(va[u + q], wiA[u], ima[q]);
          reb[q] = __fmaf_rn(vb[u + q], wrA[u], reb[q]);
          imb[q] = __fmaf_rn(vb[u + q], wiA[u], imb[q]);
        }
      }
      a0 = a1; a1 = a2; b0 = b1; b1 = b2;
    }

    const size_t magbase = ((size_t)((2*b + 0) * NF + fi) * 35 + pos) * NT;
    const size_t phbase  = ((size_t)((2*b + 1) * NF + fi) * 35 + pos) * NT;
    const float* __restrict__ wr_gf = W + (size_t)(2 * fi) * KW;
    const float* __restrict__ wi_gf = wr_gf + KW;

    // epilogue both halves: mag/phase + exact-order tie fixup
    {
      float4 mag, ph;
      float* mp = &mag.x; float* pp = &ph.x;
      mag.x = sqrtf(rea[0]*rea[0] + ima[0]*ima[0]);
      mag.y = sqrtf(rea[1]*rea[1] + ima[1]*ima[1]);
      mag.z = sqrtf(rea[2]*rea[2] + ima[2]*ima[2]);
      mag.w = sqrtf(rea[3]*rea[3] + ima[3]*ima[3]);
      ph.x = atan2f(ima[0], rea[0]);
      ph.y = atan2f(ima[1], rea[1]);
      ph.z = atan2f(ima[2], rea[2]);
      ph.w = atan2f(ima[3], rea[3]);
      #pragma unroll
      for (int q = 0; q < 4; ++q) {
        const float a = rea[q], bb = ima[q];
        if ((fabsf(bb) < DET && a < 0.f) || (a * a + bb * bb < DET2)) {
          float2 r = fixup_point(xp + ta + q, wr_gf, wi_gf);
          mp[q] = r.x; pp[q] = r.y;
        }
      }
      *(float4*)&out[magbase + ta] = mag;
      *(float4*)&out[phbase  + ta] = ph;
    }
    {
      float4 mag, ph;
      float* mp = &mag.x; float* pp = &ph.x;
      mag.x = sqrtf(reb[0]*reb[0] + imb[0]*imb[0]);
      mag.y = sqrtf(reb[1]*reb[1] + imb[1]*imb[1]);
      mag.z = sqrtf(reb[2]*reb[2] + imb[2]*imb[2]);
      mag.w = sqrtf(reb[3]*reb[3] + imb[3]*imb[3]);
      ph.x = atan2f(imb[0], reb[0]);
      ph.y = atan2f(imb[1], reb[1]);
      ph.z = atan2f(imb[2], reb[2]);
      ph.w = atan2f(imb[3], reb[3]);
      #pragma unroll
      for (int q = 0; q < 4; ++q) {
        const float a = reb[q], bb = imb[q];
        if ((fabsf(bb) < DET && a < 0.f) || (a * a + bb * bb < DET2)) {
          float2 r = fixup_point(xp + tb + q, wr_gf, wi_gf);
          mp[q] = r.x; pp[q] = r.y;
        }
      }
      *(float4*)&out[magbase + tb] = mag;
      *(float4*)&out[phbase  + tb] = ph;
    }
  }
}

extern "C" void kernel_launch(void* const* d_in, const int* in_sizes, int n_in,
                              void* d_out, int out_size, void* d_ws, size_t ws_size,
                              hipStream_t stream) {
  // Resolve inputs BY SIZE: x has 512000 elements, W has 1630720 (both fp32).
  const void* xin = d_in[0];
  const void* win = (n_in > 1) ? d_in[1] : d_in[0];
  if (n_in >= 2) {
    if (in_sizes[0] == XSIZE)      { xin = d_in[0]; win = d_in[1]; }
    else if (in_sizes[1] == XSIZE) { xin = d_in[1]; win = d_in[0]; }
  }
  const float* x = (const float*)xin;
  const float* W = (const float*)win;
  float* out = (float*)d_out;

  cwt_zero_holes<<<dim3(NB * 2 * NF * 3), dim3(TPB), 0, stream>>>(out);
  cwt_fast<<<dim3(NB * NC * FG), dim3(TPB), 0, stream>>>(x, W, out);
}

// Round 25
// 518.835 us; speedup vs baseline: 1.1239x; 1.1239x over previous
//
#include <hip/hip_runtime.h>
#include <math.h>

#define NB 8
#define NC 32
#define NF 40
#define NT 2000
#define KW 637
#define PADW 318
#define TPB 256
#define HALFT 1000
#define XLN  (NT + 2 * PADW)   // 2636 real entries
#define XLNP 2656              // zero-padded (max window over-read 2640)
#define WMAX 2720              // floats; worst group (g=0) needs 2*1348=2696
#define FG 8                   // freq groups: fi = g + FG*j (balanced taps)
#define NFG (NF / FG)          // 5 freqs per block

#define XSIZE (NB * NC * NT)   // 512000 (fp32)
#define KC 320                 // Eigen gebp kc (proven R21)

#define DET  3e-4f   // |im| margin: fast-path noise ~3e-6 -> 100x headroom
#define DET2 1e-7f   // |z|^2 near-origin margin

// canvas position (row*5+col) for each of the 32 channels; holes at 0,2,4
__device__ __constant__ int POS[32] = {
  1,3,5,6,7,8,9,10,11,13,14,15,16,12,18,19,20,21,17,22,23,24,25,26,
  27,28,29,30,31,32,33,34
};

__global__ __launch_bounds__(TPB)
void cwt_zero_holes(float* __restrict__ out) {
  int row = blockIdx.x;
  int p = (row % 3) * 2;          // hole canvas positions 0,2,4
  int rest = row / 3;
  size_t base = ((size_t)rest * 35 + p) * NT;
  float4 z = make_float4(0.f, 0.f, 0.f, 0.f);
  for (int t = threadIdx.x * 4; t < NT; t += TPB * 4)
    *(float4*)&out[base + t] = z;
}

// Exact Eigen-order recompute (kc=320, seq k-asc mul-then-add); x from LDS
// full row (window of output t starts at xp[t]), weights from global.
__device__ __noinline__ float2 fixup_point(const float* __restrict__ xv,
                                           const float* __restrict__ wr,
                                           const float* __restrict__ wi) {
  float b0r = 0.f, b0i = 0.f;
  #pragma unroll 4
  for (int k = 0; k < KC; ++k) {
    const float v = xv[k];
    b0r = __fadd_rn(b0r, __fmul_rn(wr[k], v));
    b0i = __fadd_rn(b0i, __fmul_rn(wi[k], v));
  }
  float b1r = 0.f, b1i = 0.f;
  #pragma unroll 4
  for (int k = KC; k < KW; ++k) {
    const float v = xv[k];
    b1r = __fadd_rn(b1r, __fmul_rn(wr[k], v));
    b1i = __fadd_rn(b1i, __fmul_rn(wi[k], v));
  }
  const float re = __fadd_rn(b0r, b1r);
  const float im = __fadd_rn(b0i, b1i);
  return make_float2(sqrtf(__fadd_rn(__fmul_rn(re, re), __fmul_rn(im, im))),
                     atan2f(im, re));
}

__device__ __forceinline__ void support_window(int fi, int& klo, int& kend,
                                               int& Lp) {
  const float cyc = (fi == 0) ? 4.0f
                  : (fi == 1) ? (4.0f + 2.0f / 3.0f)
                  : (fi == 2) ? (4.0f + 4.0f / 3.0f) : 6.0f;
  const float sigma = cyc / (6.283185307179586f * (float)(fi + 1));
  int h = (int)ceilf(6.0f * sigma * 250.0f);
  if (h > PADW) h = PADW;
  klo  = (PADW - h) & ~3;
  kend = PADW + h + 1;
  Lp   = (kend - klo + 3) & ~3;   // zero-padded length (multiple of 4)
}

__global__ __launch_bounds__(TPB)
void cwt_fast(const float* __restrict__ x,
              const float* __restrict__ W,
              float* __restrict__ out) {
  __shared__ __align__(16) float xp[XLNP];
  __shared__ __align__(16) float wlds[WMAX];

  const int bid = blockIdx.x;           // (b*32+c)*FG + g
  const int g   = bid & (FG - 1);
  const int bc  = bid >> 3;
  const int b   = bc >> 5;
  const int c   = bc & 31;
  const int tid = threadIdx.x;

  const float* __restrict__ xrow = x + (size_t)(b * NC + c) * NT;

  // stage FULL reflect-padded row (+ zero tail for window over-read)
  for (int i = tid; i < XLNP; i += TPB) {
    float v = 0.f;
    if (i < XLN) {
      int s = i - PADW;
      int m = (s < 0) ? -s : ((s >= NT) ? (2 * NT - 2 - s) : s);
      v = xrow[m];
    }
    xp[i] = v;
  }

  // stage this group's 5 truncated weight windows (zero-padded to 4-wide)
  {
    int woff = 0;
    for (int j = 0; j < NFG; ++j) {
      const int fi = g + FG * j;
      int klo, kend, Lp;
      support_window(fi, klo, kend, Lp);
      const float* __restrict__ wr_g = W + (size_t)(2 * fi) * KW;
      const float* __restrict__ wi_g = wr_g + KW;
      for (int i = tid; i < Lp; i += TPB) {
        const int k = klo + i;
        const bool in = k < kend;
        wlds[woff + i]      = in ? wr_g[k] : 0.f;
        wlds[woff + Lp + i] = in ? wi_g[k] : 0.f;
      }
      woff += 2 * Lp;
    }
  }
  __syncthreads();                      // the ONLY barrier

  const bool active = (tid < HALFT / 4);            // 250 threads
  const int ta = tid * 4;                            // half-0 outputs
  const int tb = tid * 4 + HALFT;                    // half-1 outputs
  const int pos = POS[c];
  const float4* __restrict__ xp4 = (const float4*)xp;

  int woff = 0;
  for (int j = 0; j < NFG; ++j) {
    const int fi = g + FG * j;
    int klo, kend, Lp;
    support_window(fi, klo, kend, Lp);
    const float* __restrict__ wr = wlds + woff;
    const float* __restrict__ wi = wr + Lp;
    woff += 2 * Lp;
    if (!active) continue;

    const int nst = Lp >> 2;
    const int ia0 = (ta + klo) >> 2;
    const int ib0 = (tb + klo) >> 2;
    float4 a0 = xp4[ia0], a1 = xp4[ia0 + 1];
    float4 b0 = xp4[ib0], b1 = xp4[ib0 + 1];

    float rea[4] = {0.f,0.f,0.f,0.f}, ima[4] = {0.f,0.f,0.f,0.f};
    float reb[4] = {0.f,0.f,0.f,0.f}, imb[4] = {0.f,0.f,0.f,0.f};

    for (int s = 0; s < nst; ++s) {
      const float4 wr4 = ((const float4*)wr)[s];   // broadcast, conflict-free
      const float4 wi4 = ((const float4*)wi)[s];
      const float4 a2 = xp4[ia0 + s + 2];          // slide prefetch
      const float4 b2 = xp4[ib0 + s + 2];
      const float va[8] = {a0.x,a0.y,a0.z,a0.w, a1.x,a1.y,a1.z,a1.w};
      const float vb[8] = {b0.x,b0.y,b0.z,b0.w, b1.x,b1.y,b1.z,b1.w};
      const float wrA[4] = {wr4.x, wr4.y, wr4.z, wr4.w};
      const float wiA[4] = {wi4.x, wi4.y, wi4.z, wi4.w};
      #pragma unroll
      for (int u = 0; u < 4; ++u) {
        #pragma unroll
        for (int q = 0; q < 4; ++q) {
          rea[q] = __fmaf_rn(va[u + q], wrA[u], rea[q]);
          ima[q] = __fmaf_rn(va[u + q], wiA[u], ima[q]);
          reb[q] = __fmaf_rn(vb[u + q], wrA[u], reb[q]);
          imb[q] = __fmaf_rn(vb[u + q], wiA[u], imb[q]);
        }
      }
      a0 = a1; a1 = a2; b0 = b1; b1 = b2;
    }

    const size_t magbase = ((size_t)((2*b + 0) * NF + fi) * 35 + pos) * NT;
    const size_t phbase  = ((size_t)((2*b + 1) * NF + fi) * 35 + pos) * NT;
    const float* __restrict__ wr_gf = W + (size_t)(2 * fi) * KW;
    const float* __restrict__ wi_gf = wr_gf + KW;

    // epilogue both halves: mag/phase + exact-order tie fixup
    {
      float4 mag, ph;
      float* mp = &mag.x; float* pp = &ph.x;
      mag.x = sqrtf(rea[0]*rea[0] + ima[0]*ima[0]);
      mag.y = sqrtf(rea[1]*rea[1] + ima[1]*ima[1]);
      mag.z = sqrtf(rea[2]*rea[2] + ima[2]*ima[2]);
      mag.w = sqrtf(rea[3]*rea[3] + ima[3]*ima[3]);
      ph.x = atan2f(ima[0], rea[0]);
      ph.y = atan2f(ima[1], rea[1]);
      ph.z = atan2f(ima[2], rea[2]);
      ph.w = atan2f(ima[3], rea[3]);
      #pragma unroll
      for (int q = 0; q < 4; ++q) {
        const float a = rea[q], bb = ima[q];
        if ((fabsf(bb) < DET && a < 0.f) || (a * a + bb * bb < DET2)) {
          float2 r = fixup_point(xp + ta + q, wr_gf, wi_gf);
          mp[q] = r.x; pp[q] = r.y;
        }
      }
      *(float4*)&out[magbase + ta] = mag;
      *(float4*)&out[phbase  + ta] = ph;
    }
    {
      float4 mag, ph;
      float* mp = &mag.x; float* pp = &ph.x;
      mag.x = sqrtf(reb[0]*reb[0] + imb[0]*imb[0]);
      mag.y = sqrtf(reb[1]*reb[1] + imb[1]*imb[1]);
      mag.z = sqrtf(reb[2]*reb[2] + imb[2]*imb[2]);
      mag.w = sqrtf(reb[3]*reb[3] + imb[3]*imb[3]);
      ph.x = atan2f(imb[0], reb[0]);
      ph.y = atan2f(imb[1], reb[1]);
      ph.z = atan2f(imb[2], reb[2]);
      ph.w = atan2f(imb[3], reb[3]);
      #pragma unroll
      for (int q = 0; q < 4; ++q) {
        const float a = reb[q], bb = imb[q];
        if ((fabsf(bb) < DET && a < 0.f) || (a * a + bb * bb < DET2)) {
          float2 r = fixup_point(xp + tb + q, wr_gf, wi_gf);
          mp[q] = r.x; pp[q] = r.y;
        }
      }
      *(float4*)&out[magbase + tb] = mag;
      *(float4*)&out[phbase  + tb] = ph;
    }
  }
}

extern "C" void kernel_launch(void* const* d_in, const int* in_sizes, int n_in,
                              void* d_out, int out_size, void* d_ws, size_t ws_size,
                              hipStream_t stream) {
  // Resolve inputs BY SIZE: x has 512000 elements, W has 1630720 (both fp32).
  const void* xin = d_in[0];
  const void* win = (n_in > 1) ? d_in[1] : d_in[0];
  if (n_in >= 2) {
    if (in_sizes[0] == XSIZE)      { xin = d_in[0]; win = d_in[1]; }
    else if (in_sizes[1] == XSIZE) { xin = d_in[1]; win = d_in[0]; }
  }
  const float* x = (const float*)xin;
  const float* W = (const float*)win;
  float* out = (float*)d_out;

  cwt_zero_holes<<<dim3(NB * 2 * NF * 3), dim3(TPB), 0, stream>>>(out);
  cwt_fast<<<dim3(NB * NC * FG), dim3(TPB), 0, stream>>>(x, W, out);
}

// Round 26
// 499.301 us; speedup vs baseline: 1.1679x; 1.0391x over previous
//
#include <hip/hip_runtime.h>
#include <math.h>

#define NB 8
#define NC 32
#define NF 40
#define NT 2000
#define KW 637
#define PADW 318
#define TPB 256
#define HALFT 1000
#define XLN  (NT + 2 * PADW)   // 2636 real entries
#define XLNP 2656              // zero-padded (max window over-read 2640)
#define WMAX 2720              // floats; worst group (g=0) needs 2*1348=2696
#define FG 8                   // freq groups: fi = g + FG*j (balanced taps)
#define NFG (NF / FG)          // 5 freqs per block

#define XSIZE (NB * NC * NT)   // 512000 (fp32)
#define KC 320                 // Eigen gebp kc (proven R21)

#define DET  3e-4f   // |im| margin: fast-path noise ~3e-6 -> 100x headroom
#define DET2 1e-7f   // |z|^2 near-origin margin

// canvas position (row*5+col) for each of the 32 channels; holes at 0,2,4
__device__ __constant__ int POS[32] = {
  1,3,5,6,7,8,9,10,11,13,14,15,16,12,18,19,20,21,17,22,23,24,25,26,
  27,28,29,30,31,32,33,34
};

__global__ __launch_bounds__(TPB)
void cwt_zero_holes(float* __restrict__ out) {
  int row = blockIdx.x;
  int p = (row % 3) * 2;          // hole canvas positions 0,2,4
  int rest = row / 3;
  size_t base = ((size_t)rest * 35 + p) * NT;
  float4 z = make_float4(0.f, 0.f, 0.f, 0.f);
  for (int t = threadIdx.x * 4; t < NT; t += TPB * 4)
    *(float4*)&out[base + t] = z;
}

// Exact Eigen-order recompute (kc=320, seq k-asc mul-then-add); x from LDS
// full row (window of output t starts at xp[t]), weights from global.
__device__ __noinline__ float2 fixup_point(const float* __restrict__ xv,
                                           const float* __restrict__ wr,
                                           const float* __restrict__ wi) {
  float b0r = 0.f, b0i = 0.f;
  #pragma unroll 4
  for (int k = 0; k < KC; ++k) {
    const float v = xv[k];
    b0r = __fadd_rn(b0r, __fmul_rn(wr[k], v));
    b0i = __fadd_rn(b0i, __fmul_rn(wi[k], v));
  }
  float b1r = 0.f, b1i = 0.f;
  #pragma unroll 4
  for (int k = KC; k < KW; ++k) {
    const float v = xv[k];
    b1r = __fadd_rn(b1r, __fmul_rn(wr[k], v));
    b1i = __fadd_rn(b1i, __fmul_rn(wi[k], v));
  }
  const float re = __fadd_rn(b0r, b1r);
  const float im = __fadd_rn(b0i, b1i);
  return make_float2(sqrtf(__fadd_rn(__fmul_rn(re, re), __fmul_rn(im, im))),
                     atan2f(im, re));
}

__device__ __forceinline__ void support_window(int fi, int& klo, int& kend,
                                               int& Lp) {
  const float cyc = (fi == 0) ? 4.0f
                  : (fi == 1) ? (4.0f + 2.0f / 3.0f)
                  : (fi == 2) ? (4.0f + 4.0f / 3.0f) : 6.0f;
  const float sigma = cyc / (6.283185307179586f * (float)(fi + 1));
  int h = (int)ceilf(6.0f * sigma * 250.0f);
  if (h > PADW) h = PADW;
  klo  = (PADW - h) & ~3;
  kend = PADW + h + 1;
  Lp   = (kend - klo + 3) & ~3;   // zero-padded length (multiple of 4)
}

__global__ __launch_bounds__(TPB)
void cwt_fast(const float* __restrict__ x,
              const float* __restrict__ W,
              float* __restrict__ out) {
  __shared__ __align__(16) float xp[XLNP];
  __shared__ __align__(16) float wlds[WMAX];

  // DIAGONAL XCD REMAP: blocks go to XCDs round-robin by blockIdx (bid%8).
  // With g = bid&7, XCD k would receive ONLY group-k blocks (1.6x work skew:
  // g=0 has fi=0's full 640-tap window). Diagonalize so every XCD sees a
  // balanced mix of groups: g = (q + r) & 7.
  const int bid = blockIdx.x;
  const int r   = bid & (FG - 1);
  const int q   = bid >> 3;             // bc index, 0..255
  const int g   = (q + r) & (FG - 1);
  const int b   = q >> 5;
  const int c   = q & 31;
  const int tid = threadIdx.x;

  const float* __restrict__ xrow = x + (size_t)(b * NC + c) * NT;

  // stage FULL reflect-padded row (+ zero tail for window over-read)
  for (int i = tid; i < XLNP; i += TPB) {
    float v = 0.f;
    if (i < XLN) {
      int s = i - PADW;
      int m = (s < 0) ? -s : ((s >= NT) ? (2 * NT - 2 - s) : s);
      v = xrow[m];
    }
    xp[i] = v;
  }

  // stage this group's 5 truncated weight windows (zero-padded to 4-wide)
  {
    int woff = 0;
    for (int j = 0; j < NFG; ++j) {
      const int fi = g + FG * j;
      int klo, kend, Lp;
      support_window(fi, klo, kend, Lp);
      const float* __restrict__ wr_g = W + (size_t)(2 * fi) * KW;
      const float* __restrict__ wi_g = wr_g + KW;
      for (int i = tid; i < Lp; i += TPB) {
        const int k = klo + i;
        const bool in = k < kend;
        wlds[woff + i]      = in ? wr_g[k] : 0.f;
        wlds[woff + Lp + i] = in ? wi_g[k] : 0.f;
      }
      woff += 2 * Lp;
    }
  }
  __syncthreads();                      // the ONLY barrier

  const bool active = (tid < HALFT / 4);            // 250 threads
  const int ta = tid * 4;                            // half-0 outputs
  const int tb = tid * 4 + HALFT;                    // half-1 outputs
  const int pos = POS[c];
  const float4* __restrict__ xp4 = (const float4*)xp;

  int woff = 0;
  for (int j = 0; j < NFG; ++j) {
    const int fi = g + FG * j;
    int klo, kend, Lp;
    support_window(fi, klo, kend, Lp);
    const float* __restrict__ wr = wlds + woff;
    const float* __restrict__ wi = wr + Lp;
    woff += 2 * Lp;
    if (!active) continue;

    const int nst = Lp >> 2;
    const int ia0 = (ta + klo) >> 2;
    const int ib0 = (tb + klo) >> 2;
    float4 a0 = xp4[ia0], a1 = xp4[ia0 + 1];
    float4 b0 = xp4[ib0], b1 = xp4[ib0 + 1];

    float rea[4] = {0.f,0.f,0.f,0.f}, ima[4] = {0.f,0.f,0.f,0.f};
    float reb[4] = {0.f,0.f,0.f,0.f}, imb[4] = {0.f,0.f,0.f,0.f};

    // unroll 2: register-renames the window slide (kills 16 v_movs/step) and
    // doubles ds_reads in flight. Per-accumulator FMA order is UNCHANGED.
    #pragma unroll 2
    for (int s = 0; s < nst; ++s) {
      const float4 wr4 = ((const float4*)wr)[s];   // broadcast, conflict-free
      const float4 wi4 = ((const float4*)wi)[s];
      const float4 a2 = xp4[ia0 + s + 2];          // slide prefetch
      const float4 b2 = xp4[ib0 + s + 2];
      const float va[8] = {a0.x,a0.y,a0.z,a0.w, a1.x,a1.y,a1.z,a1.w};
      const float vb[8] = {b0.x,b0.y,b0.z,b0.w, b1.x,b1.y,b1.z,b1.w};
      const float wrA[4] = {wr4.x, wr4.y, wr4.z, wr4.w};
      const float wiA[4] = {wi4.x, wi4.y, wi4.z, wi4.w};
      #pragma unroll
      for (int u = 0; u < 4; ++u) {
        #pragma unroll
        for (int qq = 0; qq < 4; ++qq) {
          rea[qq] = __fmaf_rn(va[u + qq], wrA[u], rea[qq]);
          ima[qq] = __fmaf_rn(va[u + qq], wiA[u], ima[qq]);
          reb[qq] = __fmaf_rn(vb[u + qq], wrA[u], reb[qq]);
          imb[qq] = __fmaf_rn(vb[u + qq], wiA[u], imb[qq]);
        }
      }
      a0 = a1; a1 = a2; b0 = b1; b1 = b2;
    }

    const size_t magbase = ((size_t)((2*b + 0) * NF + fi) * 35 + pos) * NT;
    const size_t phbase  = ((size_t)((2*b + 1) * NF + fi) * 35 + pos) * NT;
    const float* __restrict__ wr_gf = W + (size_t)(2 * fi) * KW;
    const float* __restrict__ wi_gf = wr_gf + KW;

    // epilogue both halves: mag/phase + exact-order tie fixup
    {
      float4 mag, ph;
      float* mp = &mag.x; float* pp = &ph.x;
      mag.x = sqrtf(rea[0]*rea[0] + ima[0]*ima[0]);
      mag.y = sqrtf(rea[1]*rea[1] + ima[1]*ima[1]);
      mag.z = sqrtf(rea[2]*rea[2] + ima[2]*ima[2]);
      mag.w = sqrtf(rea[3]*rea[3] + ima[3]*ima[3]);
      ph.x = atan2f(ima[0], rea[0]);
      ph.y = atan2f(ima[1], rea[1]);
      ph.z = atan2f(ima[2], rea[2]);
      ph.w = atan2f(ima[3], rea[3]);
      #pragma unroll
      for (int qq = 0; qq < 4; ++qq) {
        const float a = rea[qq], bb = ima[qq];
        if ((fabsf(bb) < DET && a < 0.f) || (a * a + bb * bb < DET2)) {
          float2 rr = fixup_point(xp + ta + qq, wr_gf, wi_gf);
          mp[qq] = rr.x; pp[qq] = rr.y;
        }
      }
      *(float4*)&out[magbase + ta] = mag;
      *(float4*)&out[phbase  + ta] = ph;
    }
    {
      float4 mag, ph;
      float* mp = &mag.x; float* pp = &ph.x;
      mag.x = sqrtf(reb[0]*reb[0] + imb[0]*imb[0]);
      mag.y = sqrtf(reb[1]*reb[1] + imb[1]*imb[1]);
      mag.z = sqrtf(reb[2]*reb[2] + imb[2]*imb[2]);
      mag.w = sqrtf(reb[3]*reb[3] + imb[3]*imb[3]);
      ph.x = atan2f(imb[0], reb[0]);
      ph.y = atan2f(imb[1], reb[1]);
      ph.z = atan2f(imb[2], reb[2]);
      ph.w = atan2f(imb[3], reb[3]);
      #pragma unroll
      for (int qq = 0; qq < 4; ++qq) {
        const float a = reb[qq], bb = imb[qq];
        if ((fabsf(bb) < DET && a < 0.f) || (a * a + bb * bb < DET2)) {
          float2 rr = fixup_point(xp + tb + qq, wr_gf, wi_gf);
          mp[qq] = rr.x; pp[qq] = rr.y;
        }
      }
      *(float4*)&out[magbase + tb] = mag;
      *(float4*)&out[phbase  + tb] = ph;
    }
  }
}

extern "C" void kernel_launch(void* const* d_in, const int* in_sizes, int n_in,
                              void* d_out, int out_size, void* d_ws, size_t ws_size,
                              hipStream_t stream) {
  // Resolve inputs BY SIZE: x has 512000 elements, W has 1630720 (both fp32).
  const void* xin = d_in[0];
  const void* win = (n_in > 1) ? d_in[1] : d_in[0];
  if (n_in >= 2) {
    if (in_sizes[0] == XSIZE)      { xin = d_in[0]; win = d_in[1]; }
    else if (in_sizes[1] == XSIZE) { xin = d_in[1]; win = d_in[0]; }
  }
  const float* x = (const float*)xin;
  const float* W = (const float*)win;
  float* out = (float*)d_out;

  cwt_zero_holes<<<dim3(NB * 2 * NF * 3), dim3(TPB), 0, stream>>>(out);
  cwt_fast<<<dim3(NB * NC * FG), dim3(TPB), 0, stream>>>(x, W, out);
}

// Round 27
// 478.354 us; speedup vs baseline: 1.2190x; 1.0438x over previous
//
#include <hip/hip_runtime.h>
#include <math.h>

#define NB 8
#define NC 32
#define NF 40
#define NT 2000
#define KW 637
#define PADW 318
#define TPB 256
#define XLN  (NT + 2 * PADW)   // 2636 real entries
#define XLNP 2656              // zero-padded (max window over-read 2647)
#define WPMAX 1364             // (wr,wi) pairs: worst group (g=0) needs 1348
#define FG 8                   // freq groups: fi = g + FG*j (balanced taps)
#define NFG (NF / FG)          // 5 freqs per block

#define XSIZE (NB * NC * NT)   // 512000 (fp32)
#define KC 320                 // Eigen gebp kc (proven R21)

#define DET  3e-4f   // |im| margin: fast-path noise ~3e-6 -> 100x headroom
#define DET2 1e-7f   // |z|^2 near-origin margin

typedef float f32x2 __attribute__((ext_vector_type(2)));

// canvas position (row*5+col) for each of the 32 channels; holes at 0,2,4
__device__ __constant__ int POS[32] = {
  1,3,5,6,7,8,9,10,11,13,14,15,16,12,18,19,20,21,17,22,23,24,25,26,
  27,28,29,30,31,32,33,34
};

// packed dual FMA: acc.lo += bcast * w.lo ; acc.hi += bcast * w.hi
// bcast = va.lo (B0) or va.hi (B1). Same IEEE rounding as v_fma_f32 per lane.
__device__ __forceinline__ void pk_fma_b0(f32x2& acc, f32x2 va, f32x2 w) {
  asm("v_pk_fma_f32 %0, %1, %2, %0 op_sel_hi:[0,1,1]"
      : "+v"(acc) : "v"(va), "v"(w));
}
__device__ __forceinline__ void pk_fma_b1(f32x2& acc, f32x2 va, f32x2 w) {
  asm("v_pk_fma_f32 %0, %1, %2, %0 op_sel:[1,0,0] op_sel_hi:[1,1,1]"
      : "+v"(acc) : "v"(va), "v"(w));
}

__global__ __launch_bounds__(TPB)
void cwt_zero_holes(float* __restrict__ out) {
  int row = blockIdx.x;
  int p = (row % 3) * 2;          // hole canvas positions 0,2,4
  int rest = row / 3;
  size_t base = ((size_t)rest * 35 + p) * NT;
  float4 z = make_float4(0.f, 0.f, 0.f, 0.f);
  for (int t = threadIdx.x * 4; t < NT; t += TPB * 4)
    *(float4*)&out[base + t] = z;
}

// Exact Eigen-order recompute (kc=320, seq k-asc mul-then-add); x from LDS
// full row, weights from global. UNCHANGED from the passing R21-R26 kernels.
__device__ __noinline__ float2 fixup_point(const float* __restrict__ xv,
                                           const float* __restrict__ wr,
                                           const float* __restrict__ wi) {
  float b0r = 0.f, b0i = 0.f;
  #pragma unroll 4
  for (int k = 0; k < KC; ++k) {
    const float v = xv[k];
    b0r = __fadd_rn(b0r, __fmul_rn(wr[k], v));
    b0i = __fadd_rn(b0i, __fmul_rn(wi[k], v));
  }
  float b1r = 0.f, b1i = 0.f;
  #pragma unroll 4
  for (int k = KC; k < KW; ++k) {
    const float v = xv[k];
    b1r = __fadd_rn(b1r, __fmul_rn(wr[k], v));
    b1i = __fadd_rn(b1i, __fmul_rn(wi[k], v));
  }
  const float re = __fadd_rn(b0r, b1r);
  const float im = __fadd_rn(b0i, b1i);
  return make_float2(sqrtf(__fadd_rn(__fmul_rn(re, re), __fmul_rn(im, im))),
                     atan2f(im, re));
}

__device__ __forceinline__ void support_window(int fi, int& klo, int& kend,
                                               int& Lp) {
  const float cyc = (fi == 0) ? 4.0f
                  : (fi == 1) ? (4.0f + 2.0f / 3.0f)
                  : (fi == 2) ? (4.0f + 4.0f / 3.0f) : 6.0f;
  const float sigma = cyc / (6.283185307179586f * (float)(fi + 1));
  int h = (int)ceilf(6.0f * sigma * 250.0f);
  if (h > PADW) h = PADW;
  klo  = (PADW - h) & ~3;
  kend = PADW + h + 1;
  Lp   = (kend - klo + 3) & ~3;   // zero-padded length (multiple of 4)
}

__global__ __launch_bounds__(TPB)
void cwt_fast(const float* __restrict__ x,
              const float* __restrict__ W,
              float* __restrict__ out) {
  __shared__ __align__(16) float xp[XLNP];
  __shared__ __align__(16) f32x2 wl2[WPMAX];   // interleaved (wr,wi) pairs

  // diagonal XCD remap (R25): balance groups across XCDs
  const int bid = blockIdx.x;
  const int r   = bid & (FG - 1);
  const int q   = bid >> 3;             // bc index, 0..255
  const int g   = (q + r) & (FG - 1);
  const int b   = q >> 5;
  const int c   = q & 31;
  const int tid = threadIdx.x;

  const float* __restrict__ xrow = x + (size_t)(b * NC + c) * NT;

  // stage FULL reflect-padded row (+ zero tail for window over-read)
  for (int i = tid; i < XLNP; i += TPB) {
    float v = 0.f;
    if (i < XLN) {
      int s = i - PADW;
      int m = (s < 0) ? -s : ((s >= NT) ? (2 * NT - 2 - s) : s);
      v = xrow[m];
    }
    xp[i] = v;
  }

  // stage this group's 5 truncated weight windows as (wr,wi) PAIRS,
  // zero-padded to 4-tap multiples
  {
    int woffp = 0;
    for (int j = 0; j < NFG; ++j) {
      const int fi = g + FG * j;
      int klo, kend, Lp;
      support_window(fi, klo, kend, Lp);
      const float* __restrict__ wr_g = W + (size_t)(2 * fi) * KW;
      const float* __restrict__ wi_g = wr_g + KW;
      for (int i = tid; i < Lp; i += TPB) {
        const int k = klo + i;
        const bool in = k < kend;
        f32x2 p;
        p.x = in ? wr_g[k] : 0.f;
        p.y = in ? wi_g[k] : 0.f;
        wl2[woffp + i] = p;
      }
      woffp += Lp;
    }
    // zero the prefetch over-run region past the last freq
    for (int i = woffp + tid; i < WPMAX; i += TPB) {
      f32x2 z; z.x = 0.f; z.y = 0.f;
      wl2[i] = z;
    }
  }
  __syncthreads();                      // the ONLY barrier

  const bool active = (tid < NT / 8);   // 250 threads, 8 outputs each
  const int ta = tid * 8;
  const int pos = POS[c];
  const float4* __restrict__ xp4 = (const float4*)xp;

  int woffp = 0;
  for (int j = 0; j < NFG; ++j) {
    const int fi = g + FG * j;
    int klo, kend, Lp;
    support_window(fi, klo, kend, Lp);
    const float4* __restrict__ wq4 = (const float4*)(wl2 + woffp); // 2 pairs ea
    woffp += Lp;
    if (!active) continue;

    const int nst = Lp >> 2;
    const float4* __restrict__ xq = xp4 + ((ta + klo) >> 2);

    // window ring (2-step lookahead) + weight ring (2-step lookahead)
    float4 r0 = xq[0], r1 = xq[1], r2 = xq[2], r3 = xq[3];
    float4 w0 = wq4[0], w1 = wq4[1], w2 = wq4[2], w3 = wq4[3];

    f32x2 acc[8];
    #pragma unroll
    for (int qq = 0; qq < 8; ++qq) { acc[qq].x = 0.f; acc[qq].y = 0.f; }

    #pragma unroll 4
    for (int s = 0; s < nst; ++s) {
      const float4 rn  = xq[s + 4];          // used at s+2
      const float4 wn0 = wq4[2 * s + 4];     // used at s+2
      const float4 wn1 = wq4[2 * s + 5];

      // window pairs P[0..5] = floats [4s .. 4s+11]; taps WT[0..3] = 4s..4s+3
      f32x2 P[6], WT[4];
      P[0].x = r0.x; P[0].y = r0.y;  P[1].x = r0.z; P[1].y = r0.w;
      P[2].x = r1.x; P[2].y = r1.y;  P[3].x = r1.z; P[3].y = r1.w;
      P[4].x = r2.x; P[4].y = r2.y;  P[5].x = r2.z; P[5].y = r2.w;
      WT[0].x = w0.x; WT[0].y = w0.y;  WT[1].x = w0.z; WT[1].y = w0.w;
      WT[2].x = w1.x; WT[2].y = w1.y;  WT[3].x = w1.z; WT[3].y = w1.w;

      #pragma unroll
      for (int u = 0; u < 4; ++u) {
        #pragma unroll
        for (int qq = 0; qq < 8; ++qq) {
          const int jj = u + qq;
          if (jj & 1) pk_fma_b1(acc[qq], P[jj >> 1], WT[u]);
          else        pk_fma_b0(acc[qq], P[jj >> 1], WT[u]);
        }
      }
      r0 = r1; r1 = r2; r2 = r3; r3 = rn;
      w0 = w2; w1 = w3; w2 = wn0; w3 = wn1;
    }

    const size_t magbase = ((size_t)((2*b + 0) * NF + fi) * 35 + pos) * NT;
    const size_t phbase  = ((size_t)((2*b + 1) * NF + fi) * 35 + pos) * NT;
    const float* __restrict__ wr_gf = W + (size_t)(2 * fi) * KW;
    const float* __restrict__ wi_gf = wr_gf + KW;

    float mg[8], ph[8];
    #pragma unroll
    for (int qq = 0; qq < 8; ++qq) {
      const float a = acc[qq].x, bb = acc[qq].y;
      mg[qq] = sqrtf(a * a + bb * bb);
      ph[qq] = atan2f(bb, a);
      if ((fabsf(bb) < DET && a < 0.f) || (a * a + bb * bb < DET2)) {
        float2 rr = fixup_point(xp + ta + qq, wr_gf, wi_gf);
        mg[qq] = rr.x; ph[qq] = rr.y;
      }
    }
    *(float4*)&out[magbase + ta]     = make_float4(mg[0], mg[1], mg[2], mg[3]);
    *(float4*)&out[magbase + ta + 4] = make_float4(mg[4], mg[5], mg[6], mg[7]);
    *(float4*)&out[phbase  + ta]     = make_float4(ph[0], ph[1], ph[2], ph[3]);
    *(float4*)&out[phbase  + ta + 4] = make_float4(ph[4], ph[5], ph[6], ph[7]);
  }
}

extern "C" void kernel_launch(void* const* d_in, const int* in_sizes, int n_in,
                              void* d_out, int out_size, void* d_ws, size_t ws_size,
                              hipStream_t stream) {
  // Resolve inputs BY SIZE: x has 512000 elements, W has 1630720 (both fp32).
  const void* xin = d_in[0];
  const void* win = (n_in > 1) ? d_in[1] : d_in[0];
  if (n_in >= 2) {
    if (in_sizes[0] == XSIZE)      { xin = d_in[0]; win = d_in[1]; }
    else if (in_sizes[1] == XSIZE) { xin = d_in[1]; win = d_in[0]; }
  }
  const float* x = (const float*)xin;
  const float* W = (const float*)win;
  float* out = (float*)d_out;

  cwt_zero_holes<<<dim3(NB * 2 * NF * 3), dim3(TPB), 0, stream>>>(out);
  cwt_fast<<<dim3(NB * NC * FG), dim3(TPB), 0, stream>>>(x, W, out);
}

// Round 28
// 463.265 us; speedup vs baseline: 1.2587x; 1.0326x over previous
//
#include <hip/hip_runtime.h>
#include <math.h>

#define NB 8
#define NC 32
#define NF 40
#define NT 2000
#define KW 637
#define PADW 318
#define TPB 512
#define XLN  (NT + 2 * PADW)   // 2636 real entries
#define XLNP 2656              // zero-padded (max window over-read 2639)
#define WPMAX 1364             // (wr,wi) pairs: worst group (g=0) needs 1348
#define FG 8                   // freq groups: fi = g + FG*j (balanced taps)
#define NFG (NF / FG)          // 5 freqs per block

#define XSIZE (NB * NC * NT)   // 512000 (fp32)
#define KC 320                 // Eigen gebp kc (proven R21)

#define DET  3e-4f   // |im| margin: fast-path noise ~3e-6 -> 100x headroom
#define DET2 1e-7f   // |z|^2 near-origin margin

typedef float f32x2 __attribute__((ext_vector_type(2)));

// canvas position (row*5+col) for each of the 32 channels; holes at 0,2,4
__device__ __constant__ int POS[32] = {
  1,3,5,6,7,8,9,10,11,13,14,15,16,12,18,19,20,21,17,22,23,24,25,26,
  27,28,29,30,31,32,33,34
};

// packed dual FMA (HW-validated R27): acc.lo += x * w.lo ; acc.hi += x * w.hi
// where x = va.lo (b0) or va.hi (b1). IEEE-identical to v_fma_f32 per lane.
__device__ __forceinline__ void pk_fma_b0(f32x2& acc, f32x2 va, f32x2 w) {
  asm("v_pk_fma_f32 %0, %1, %2, %0 op_sel_hi:[0,1,1]"
      : "+v"(acc) : "v"(va), "v"(w));
}
__device__ __forceinline__ void pk_fma_b1(f32x2& acc, f32x2 va, f32x2 w) {
  asm("v_pk_fma_f32 %0, %1, %2, %0 op_sel:[1,0,0] op_sel_hi:[1,1,1]"
      : "+v"(acc) : "v"(va), "v"(w));
}

__global__ __launch_bounds__(256)
void cwt_zero_holes(float* __restrict__ out) {
  int row = blockIdx.x;
  int p = (row % 3) * 2;          // hole canvas positions 0,2,4
  int rest = row / 3;
  size_t base = ((size_t)rest * 35 + p) * NT;
  float4 z = make_float4(0.f, 0.f, 0.f, 0.f);
  for (int t = threadIdx.x * 4; t < NT; t += 256 * 4)
    *(float4*)&out[base + t] = z;
}

// Exact Eigen-order recompute (kc=320, seq k-asc mul-then-add); x from LDS
// full row, weights from global. UNCHANGED from the passing R21-R27 kernels.
__device__ __noinline__ float2 fixup_point(const float* __restrict__ xv,
                                           const float* __restrict__ wr,
                                           const float* __restrict__ wi) {
  float b0r = 0.f, b0i = 0.f;
  #pragma unroll 4
  for (int k = 0; k < KC; ++k) {
    const float v = xv[k];
    b0r = __fadd_rn(b0r, __fmul_rn(wr[k], v));
    b0i = __fadd_rn(b0i, __fmul_rn(wi[k], v));
  }
  float b1r = 0.f, b1i = 0.f;
  #pragma unroll 4
  for (int k = KC; k < KW; ++k) {
    const float v = xv[k];
    b1r = __fadd_rn(b1r, __fmul_rn(wr[k], v));
    b1i = __fadd_rn(b1i, __fmul_rn(wi[k], v));
  }
  const float re = __fadd_rn(b0r, b1r);
  const float im = __fadd_rn(b0i, b1i);
  return make_float2(sqrtf(__fadd_rn(__fmul_rn(re, re), __fmul_rn(im, im))),
                     atan2f(im, re));
}

__device__ __forceinline__ void support_window(int fi, int& klo, int& kend,
                                               int& Lp) {
  const float cyc = (fi == 0) ? 4.0f
                  : (fi == 1) ? (4.0f + 2.0f / 3.0f)
                  : (fi == 2) ? (4.0f + 4.0f / 3.0f) : 6.0f;
  const float sigma = cyc / (6.283185307179586f * (float)(fi + 1));
  int h = (int)ceilf(6.0f * sigma * 250.0f);
  if (h > PADW) h = PADW;
  klo  = (PADW - h) & ~3;
  kend = PADW + h + 1;
  Lp   = (kend - klo + 3) & ~3;   // zero-padded length (multiple of 4)
}

__global__ __launch_bounds__(TPB)
void cwt_fast(const float* __restrict__ x,
              const float* __restrict__ W,
              float* __restrict__ out) {
  __shared__ __align__(16) float xp[XLNP];
  __shared__ __align__(16) f32x2 wl2[WPMAX];   // interleaved (wr,wi) pairs

  // diagonal XCD remap (R25): balance groups across XCDs
  const int bid = blockIdx.x;
  const int r   = bid & (FG - 1);
  const int q   = bid >> 3;             // bc index, 0..255
  const int g   = (q + r) & (FG - 1);
  const int b   = q >> 5;
  const int c   = q & 31;
  const int tid = threadIdx.x;

  const float* __restrict__ xrow = x + (size_t)(b * NC + c) * NT;

  // stage FULL reflect-padded row (+ zero tail for window over-read)
  for (int i = tid; i < XLNP; i += TPB) {
    float v = 0.f;
    if (i < XLN) {
      int s = i - PADW;
      int m = (s < 0) ? -s : ((s >= NT) ? (2 * NT - 2 - s) : s);
      v = xrow[m];
    }
    xp[i] = v;
  }

  // stage this group's 5 truncated weight windows as (wr,wi) PAIRS
  {
    int woffp = 0;
    for (int j = 0; j < NFG; ++j) {
      const int fi = g + FG * j;
      int klo, kend, Lp;
      support_window(fi, klo, kend, Lp);
      const float* __restrict__ wr_g = W + (size_t)(2 * fi) * KW;
      const float* __restrict__ wi_g = wr_g + KW;
      for (int i = tid; i < Lp; i += TPB) {
        const int k = klo + i;
        const bool in = k < kend;
        f32x2 p;
        p.x = in ? wr_g[k] : 0.f;
        p.y = in ? wi_g[k] : 0.f;
        wl2[woffp + i] = p;
      }
      woffp += Lp;
    }
    for (int i = woffp + tid; i < WPMAX; i += TPB) {
      f32x2 z; z.x = 0.f; z.y = 0.f;
      wl2[i] = z;
    }
  }
  __syncthreads();                      // the ONLY barrier

  const bool active = (tid < NT / 4);   // 500 threads, 4 outputs each
  const int ta = tid * 4;
  const int pos = POS[c];
  const float4* __restrict__ xp4 = (const float4*)xp;

  int woffp = 0;
  for (int j = 0; j < NFG; ++j) {
    const int fi = g + FG * j;
    int klo, kend, Lp;
    support_window(fi, klo, kend, Lp);
    const float4* __restrict__ wq4 = (const float4*)(wl2 + woffp); // 2 pairs ea
    woffp += Lp;
    if (!active) continue;

    const int nst = Lp >> 2;
    const float4* __restrict__ xq = xp4 + ((ta + klo) >> 2);  // 16B stride

    f32x2 acc[4];
    #pragma unroll
    for (int qq = 0; qq < 4; ++qq) { acc[qq].x = 0.f; acc[qq].y = 0.f; }

    // no rings: direct indexing + unroll -> compiler CSEs xq[s+1] across
    // steps and batch-hoists LDS loads (deep lookahead, zero slide movs)
    #pragma unroll 8
    for (int s = 0; s < nst; ++s) {
      const float4 w01 = wq4[2 * s];       // taps ks..ks+1 (pairs)
      const float4 w23 = wq4[2 * s + 1];   // taps ks+2..ks+3
      const float4 rA = xq[s];             // window floats 0..3 (rel)
      const float4 rB = xq[s + 1];         // window floats 4..7
      f32x2 xA0; xA0.x = rA.x; xA0.y = rA.y;
      f32x2 xA1; xA1.x = rA.z; xA1.y = rA.w;
      f32x2 xB0; xB0.x = rB.x; xB0.y = rB.y;
      f32x2 xB1; xB1.x = rB.z; xB1.y = rB.w;
      f32x2 wp0; wp0.x = w01.x; wp0.y = w01.y;
      f32x2 wp1; wp1.x = w01.z; wp1.y = w01.w;
      f32x2 wp2; wp2.x = w23.x; wp2.y = w23.y;
      f32x2 wp3; wp3.x = w23.z; wp3.y = w23.w;
      // tap u, output q consumes window float (u+q); k-ascending per acc
      pk_fma_b0(acc[0], xA0, wp0); pk_fma_b1(acc[1], xA0, wp0);
      pk_fma_b0(acc[2], xA1, wp0); pk_fma_b1(acc[3], xA1, wp0);
      pk_fma_b1(acc[0], xA0, wp1); pk_fma_b0(acc[1], xA1, wp1);
      pk_fma_b1(acc[2], xA1, wp1); pk_fma_b0(acc[3], xB0, wp1);
      pk_fma_b0(acc[0], xA1, wp2); pk_fma_b1(acc[1], xA1, wp2);
      pk_fma_b0(acc[2], xB0, wp2); pk_fma_b1(acc[3], xB0, wp2);
      pk_fma_b1(acc[0], xA1, wp3); pk_fma_b0(acc[1], xB0, wp3);
      pk_fma_b1(acc[2], xB0, wp3); pk_fma_b0(acc[3], xB1, wp3);
    }

    const size_t magbase = ((size_t)((2*b + 0) * NF + fi) * 35 + pos) * NT;
    const size_t phbase  = ((size_t)((2*b + 1) * NF + fi) * 35 + pos) * NT;
    const float* __restrict__ wr_gf = W + (size_t)(2 * fi) * KW;
    const float* __restrict__ wi_gf = wr_gf + KW;

    float mg[4], ph[4];
    #pragma unroll
    for (int qq = 0; qq < 4; ++qq) {
      const float a = acc[qq].x, bb = acc[qq].y;
      mg[qq] = sqrtf(a * a + bb * bb);
      ph[qq] = atan2f(bb, a);
      if ((fabsf(bb) < DET && a < 0.f) || (a * a + bb * bb < DET2)) {
        float2 rr = fixup_point(xp + ta + qq, wr_gf, wi_gf);
        mg[qq] = rr.x; ph[qq] = rr.y;
      }
    }
    *(float4*)&out[magbase + ta] = make_float4(mg[0], mg[1], mg[2], mg[3]);
    *(float4*)&out[phbase  + ta] = make_float4(ph[0], ph[1], ph[2], ph[3]);
  }
}

extern "C" void kernel_launch(void* const* d_in, const int* in_sizes, int n_in,
                              void* d_out, int out_size, void* d_ws, size_t ws_size,
                              hipStream_t stream) {
  // Resolve inputs BY SIZE: x has 512000 elements, W has 1630720 (both fp32).
  const void* xin = d_in[0];
  const void* win = (n_in > 1) ? d_in[1] : d_in[0];
  if (n_in >= 2) {
    if (in_sizes[0] == XSIZE)      { xin = d_in[0]; win = d_in[1]; }
    else if (in_sizes[1] == XSIZE) { xin = d_in[1]; win = d_in[0]; }
  }
  const float* x = (const float*)xin;
  const float* W = (const float*)win;
  float* out = (float*)d_out;

  cwt_zero_holes<<<dim3(NB * 2 * NF * 3), dim3(256), 0, stream>>>(out);
  cwt_fast<<<dim3(NB * NC * FG), dim3(TPB), 0, stream>>>(x, W, out);
}